// Round 1
// baseline (613.640 us; speedup 1.0000x reference)
//
#include <hip/hip_runtime.h>

// NCC forces, 256^3 fp32, box window 5x5x5 (zero-padded), symmetric gradients.
// Fully fused: one kernel, no workspace. Each block: 32x8 (x,y) tile, marches
// a 64-deep z chunk with LDS plane rings (raw: 4 deep, xy-box-filtered: 5 deep).

#define DIM 256
#define TX  32
#define TY  8
#define ZCH 64
#define PX  (TX + 4)   // 36, x halo +-2
#define PY  (TY + 4)   // 12, y halo +-2
#define NT  256

__global__ __launch_bounds__(NT) void ncc_forces_kernel(
    const float* __restrict__ gI,
    const float* __restrict__ gR,
    float* __restrict__ gOut)
{
    // raw image/ref planes, ring of 4 (need z-3..z for gradients at zc=z-2)
    __shared__ float rawI[4][PY][PX];
    __shared__ float rawR[4][PY][PX];
    // x-filtered 5 fields for the current plane (y halo kept)
    __shared__ float xtmp[5][PY][TX];
    // xy-box-filtered 5 fields, ring of 5 z-planes
    __shared__ float bxy[5][5][TY][TX];

    const int t  = threadIdx.x;
    const int tx = t & (TX - 1);
    const int ty = t / TX;
    const int x0 = blockIdx.x * TX;
    const int y0 = blockIdx.y * TY;
    const int z0 = blockIdx.z * ZCH;

    for (int z = z0 - 2; z < z0 + ZCH + 2; ++z) {
        const int sraw = (z + 4) & 3;        // z >= -2 so z+4 >= 2
        const int sbox = (z + 10) % 5;

        // ---- A: load raw plane z (zeros outside the volume) ----
        if ((unsigned)z < DIM) {
            const float* bI = gI + (size_t)z * DIM * DIM;
            const float* bR = gR + (size_t)z * DIM * DIM;
            for (int idx = t; idx < PY * PX; idx += NT) {
                const int ly = idx / PX;
                const int lx = idx - ly * PX;
                const int gx = x0 - 2 + lx;
                const int gy = y0 - 2 + ly;
                float vi = 0.f, vr = 0.f;
                if ((unsigned)gx < DIM && (unsigned)gy < DIM) {
                    const int o = gy * DIM + gx;
                    vi = bI[o];
                    vr = bR[o];
                }
                rawI[sraw][ly][lx] = vi;
                rawR[sraw][ly][lx] = vr;
            }
        } else {
            for (int idx = t; idx < PY * PX; idx += NT) {
                const int ly = idx / PX;
                const int lx = idx - ly * PX;
                rawI[sraw][ly][lx] = 0.f;
                rawR[sraw][ly][lx] = 0.f;
            }
        }
        __syncthreads();

        // ---- B: x-direction 5-wide box sums of the five fields ----
        for (int idx = t; idx < PY * TX; idx += NT) {
            const int ly = idx / TX;
            const int lx = idx - ly * TX;
            float s0 = 0.f, s1 = 0.f, s2 = 0.f, s3 = 0.f, s4 = 0.f;
            #pragma unroll
            for (int dx = 0; dx < 5; ++dx) {
                const float a = rawI[sraw][ly][lx + dx];
                const float b = rawR[sraw][ly][lx + dx];
                s0 += a; s1 += b; s2 += a * a; s3 += b * b; s4 += a * b;
            }
            xtmp[0][ly][lx] = s0;
            xtmp[1][ly][lx] = s1;
            xtmp[2][ly][lx] = s2;
            xtmp[3][ly][lx] = s3;
            xtmp[4][ly][lx] = s4;
        }
        __syncthreads();

        // ---- C: y-direction 5-wide box sums -> bxy ring slot for plane z ----
        #pragma unroll
        for (int f = 0; f < 5; ++f) {
            float s = 0.f;
            #pragma unroll
            for (int dy = 0; dy < 5; ++dy) s += xtmp[f][ty + dy][tx];
            bxy[sbox][f][ty][tx] = s;
        }
        __syncthreads();

        // ---- D: finalize output plane zc = z - 2 ----
        const int zc = z - 2;
        if (zc >= z0) {
            // z-box: window zc-2..zc+2 == all five ring slots (OOR planes are 0)
            float s[5];
            #pragma unroll
            for (int f = 0; f < 5; ++f) {
                s[f] = bxy[0][f][ty][tx] + bxy[1][f][ty][tx] + bxy[2][f][ty][tx]
                     + bxy[3][f][ty][tx] + bxy[4][f][ty][tx];
            }
            // faithful to reference: reference_image_mean uses sum_i (their bug)
            const float m     = s[0] * (1.0f / 125.0f);
            const float var_r = s[3] - 2.0f * m * s[1] + 125.0f * m * m;
            const float var_i = s[2] - 2.0f * m * s[0] + 125.0f * m * m;
            const float cross = s[4] - m * s[0] - m * s[1] + 125.0f * m * m;

            const int sc  = (zc + 4) & 3;   // plane zc
            const int smi = (zc + 3) & 3;   // plane zc-1
            const int spl = (zc + 5) & 3;   // plane zc+1
            const int ly = ty + 2, lx = tx + 2;

            const float ic = rawI[sc][ly][lx];
            const float rc = rawR[sc][ly][lx];

            // gradients: central inside, one-sided at global edges
            float giz, grz;
            if (zc == 0) {
                giz = rawI[spl][ly][lx] - ic;
                grz = rawR[spl][ly][lx] - rc;
            } else if (zc == DIM - 1) {
                giz = ic - rawI[smi][ly][lx];
                grz = rc - rawR[smi][ly][lx];
            } else {
                giz = 0.5f * (rawI[spl][ly][lx] - rawI[smi][ly][lx]);
                grz = 0.5f * (rawR[spl][ly][lx] - rawR[smi][ly][lx]);
            }

            const int gy = y0 + ty;
            float giy, gry;
            if (gy == 0) {
                giy = rawI[sc][ly + 1][lx] - ic;
                gry = rawR[sc][ly + 1][lx] - rc;
            } else if (gy == DIM - 1) {
                giy = ic - rawI[sc][ly - 1][lx];
                gry = rc - rawR[sc][ly - 1][lx];
            } else {
                giy = 0.5f * (rawI[sc][ly + 1][lx] - rawI[sc][ly - 1][lx]);
                gry = 0.5f * (rawR[sc][ly + 1][lx] - rawR[sc][ly - 1][lx]);
            }

            const int gx = x0 + tx;
            float gix, grx;
            if (gx == 0) {
                gix = rawI[sc][ly][lx + 1] - ic;
                grx = rawR[sc][ly][lx + 1] - rc;
            } else if (gx == DIM - 1) {
                gix = ic - rawI[sc][ly][lx - 1];
                grx = rc - rawR[sc][ly][lx - 1];
            } else {
                gix = 0.5f * (rawI[sc][ly][lx + 1] - rawI[sc][ly][lx - 1]);
                grx = 0.5f * (rawR[sc][ly][lx + 1] - rawR[sc][ly][lx - 1]);
            }

            const float factor = 2.0f * cross / (var_i * var_r + 1e-6f)
                               * (ic - cross / var_r * rc);

            const size_t CS   = (size_t)DIM * DIM * DIM;
            const size_t base = ((size_t)zc * DIM + gy) * DIM + gx;
            gOut[base]          = -factor * 0.5f * (giz + grz);
            gOut[base + CS]     = -factor * 0.5f * (giy + gry);
            gOut[base + 2 * CS] = -factor * 0.5f * (gix + grx);
        }
        __syncthreads();  // protect rings before next iteration overwrites
    }
}

extern "C" void kernel_launch(void* const* d_in, const int* in_sizes, int n_in,
                              void* d_out, int out_size, void* d_ws, size_t ws_size,
                              hipStream_t stream) {
    const float* img = (const float*)d_in[0];  // image
    // d_in[1] = mask (unused by reference)
    const float* ref = (const float*)d_in[2];  // reference_image
    // d_in[3] = reference_mask (unused by reference)
    float* out = (float*)d_out;

    dim3 grid(DIM / TX, DIM / TY, DIM / ZCH);  // 8 x 32 x 4 = 1024 blocks
    ncc_forces_kernel<<<grid, NT, 0, stream>>>(img, ref, out);
}

// Round 2
// 399.793 us; speedup vs baseline: 1.5349x; 1.5349x over previous
//
#include <hip/hip_runtime.h>

// NCC forces, 256^3 fp32, 5x5x5 zero-padded box window, symmetric gradients.
// Fused single kernel. Per block: 32x8 (x,y) tile marching 64 z-planes.
//  - raw planes: 5-slot LDS ring, 40-wide (16B-aligned halo), float4 prefetch
//    pipelined one plane ahead in registers.
//  - y-box sums -> LDS ytmp; x-box + z-window (5-deep register history) +
//    finalize in one phase. 2 barriers per z-step.

#define DIM 256
#define TX  32
#define TY  8
#define ZCH 64
#define PXA 40   // x: gx in [x0-4, x0+36), 16B-aligned float4 chunks
#define PY  12   // y: gy in [y0-2, y0+10)
#define NT  256
#define RS  5    // raw ring slots

__global__ __launch_bounds__(NT, 4) void ncc_forces_kernel(
    const float* __restrict__ gI,
    const float* __restrict__ gR,
    float* __restrict__ gOut)
{
    __shared__ __align__(16) float rawI[RS][PY][PXA];
    __shared__ __align__(16) float rawR[RS][PY][PXA];
    __shared__ float ytmp[5][TY][PXA];

    const int t  = threadIdx.x;
    const int tx = t & 31;
    const int ty = t >> 5;
    const int x0 = blockIdx.x * TX;
    const int y0 = blockIdx.y * TY;
    const int z0 = blockIdx.z * ZCH;

    // ---- prefetch role: threads 0..119 load I, 128..247 load R (one float4 each) ----
    const bool pfI   = (t < 120);
    const bool pfR   = (t >= 128 && t < 248);
    const bool pfAct = pfI || pfR;
    const int  pid   = pfI ? t : (t - 128);
    const int  prow  = pid / 10;
    const int  pcol  = (pid - prow * 10) * 4;
    const int  pgy   = y0 - 2 + prow;
    const int  pgx   = x0 - 4 + pcol;
    const float* pbase = pfI ? gI : gR;
    float*       praw  = pfI ? &rawI[0][0][0] : &rawR[0][0][0];
    const bool   pxyOk = ((unsigned)pgy < DIM) && ((unsigned)pgx < DIM);

    // ---- y-box role: threads 0..159, two adjacent columns each ----
    const bool bAct = (t < 160);
    const int  brow = t / 20;                 // 0..7
    const int  bcol = (t - brow * 20) * 2;    // 0,2,..,38

    float4 pf = make_float4(0.f, 0.f, 0.f, 0.f);

    // ---- prologue: plane z0-2 direct to LDS; plane z0-1 into pf regs ----
    if (pfAct) {
        float4 v = make_float4(0.f, 0.f, 0.f, 0.f);
        const int zp0 = z0 - 2;
        if (zp0 >= 0 && pxyOk)
            v = *(const float4*)(pbase + (((size_t)zp0 * DIM + pgy) * DIM + pgx));
        *(float4*)(praw + (((z0 - 2 + 10) % RS) * PY + prow) * PXA + pcol) = v;
        const int zp1 = z0 - 1;
        if (zp1 >= 0 && pxyOk)
            pf = *(const float4*)(pbase + (((size_t)zp1 * DIM + pgy) * DIM + pgx));
    }

    // z-window history: xy-sums of planes z-4..z-1 (zeros before chunk start)
    float h[4][5];
    #pragma unroll
    for (int j = 0; j < 4; ++j)
        #pragma unroll
        for (int f = 0; f < 5; ++f) h[j][f] = 0.f;

    __syncthreads();

    for (int z = z0 - 2; z < z0 + ZCH + 2; ++z) {
        const int sz  = (z + 10) % RS;   // slot of plane z
        const int szn = (z + 11) % RS;   // slot for plane z+1

        // A: commit prefetched plane z+1, then issue load of plane z+2
        if (pfAct) {
            *(float4*)(praw + (szn * PY + prow) * PXA + pcol) = pf;
            float4 v = make_float4(0.f, 0.f, 0.f, 0.f);
            const int zp = z + 2;
            if (zp < DIM && pxyOk)
                v = *(const float4*)(pbase + (((size_t)zp * DIM + pgy) * DIM + pgx));
            pf = v;
        }

        // B: y-direction 5-wide box sums of the five fields for plane z
        if (bAct) {
            float sA0=0.f,sA1=0.f,sB0=0.f,sB1=0.f,sAA0=0.f,sAA1=0.f,
                  sBB0=0.f,sBB1=0.f,sAB0=0.f,sAB1=0.f;
            #pragma unroll
            for (int dy = 0; dy < 5; ++dy) {
                const float aI0 = rawI[sz][brow + dy][bcol];
                const float aI1 = rawI[sz][brow + dy][bcol + 1];
                const float aR0 = rawR[sz][brow + dy][bcol];
                const float aR1 = rawR[sz][brow + dy][bcol + 1];
                sA0 += aI0; sA1 += aI1; sB0 += aR0; sB1 += aR1;
                sAA0 = fmaf(aI0, aI0, sAA0); sAA1 = fmaf(aI1, aI1, sAA1);
                sBB0 = fmaf(aR0, aR0, sBB0); sBB1 = fmaf(aR1, aR1, sBB1);
                sAB0 = fmaf(aI0, aR0, sAB0); sAB1 = fmaf(aI1, aR1, sAB1);
            }
            ytmp[0][brow][bcol] = sA0;  ytmp[0][brow][bcol + 1] = sA1;
            ytmp[1][brow][bcol] = sB0;  ytmp[1][brow][bcol + 1] = sB1;
            ytmp[2][brow][bcol] = sAA0; ytmp[2][brow][bcol + 1] = sAA1;
            ytmp[3][brow][bcol] = sBB0; ytmp[3][brow][bcol + 1] = sBB1;
            ytmp[4][brow][bcol] = sAB0; ytmp[4][brow][bcol + 1] = sAB1;
        }
        __syncthreads();

        // C: x-direction box sums (center lx = tx+4, window tx+2..tx+6)
        float n[5];
        #pragma unroll
        for (int f = 0; f < 5; ++f) {
            const float* yp = &ytmp[f][ty][tx];
            n[f] = yp[2] + yp[3] + yp[4] + yp[5] + yp[6];
        }

        // D: finalize output plane zc = z-2
        const int zc = z - 2;
        if (zc >= z0) {
            float zs[5];
            #pragma unroll
            for (int f = 0; f < 5; ++f)
                zs[f] = h[0][f] + h[1][f] + h[2][f] + h[3][f] + n[f];

            // faithful to reference: reference_image_mean uses sum_i (their bug)
            const float m     = zs[0] * (1.0f / 125.0f);
            const float var_r = zs[3] - 2.0f * m * zs[1] + 125.0f * m * m;
            const float var_i = zs[2] - 2.0f * m * zs[0] + 125.0f * m * m;
            const float cross = zs[4] - m * zs[0] - m * zs[1] + 125.0f * m * m;

            const int sc = (zc + 10) % RS;
            const int sm = (zc + 9)  % RS;
            const int sp = (zc + 11) % RS;
            const int ly = ty + 2, lx = tx + 4;

            const float ic = rawI[sc][ly][lx];
            const float rc = rawR[sc][ly][lx];

            float giz, grz;
            if (zc == 0) {
                giz = rawI[sp][ly][lx] - ic;
                grz = rawR[sp][ly][lx] - rc;
            } else if (zc == DIM - 1) {
                giz = ic - rawI[sm][ly][lx];
                grz = rc - rawR[sm][ly][lx];
            } else {
                giz = 0.5f * (rawI[sp][ly][lx] - rawI[sm][ly][lx]);
                grz = 0.5f * (rawR[sp][ly][lx] - rawR[sm][ly][lx]);
            }

            const int gy = y0 + ty;
            float giy, gry;
            if (gy == 0) {
                giy = rawI[sc][ly + 1][lx] - ic;
                gry = rawR[sc][ly + 1][lx] - rc;
            } else if (gy == DIM - 1) {
                giy = ic - rawI[sc][ly - 1][lx];
                gry = rc - rawR[sc][ly - 1][lx];
            } else {
                giy = 0.5f * (rawI[sc][ly + 1][lx] - rawI[sc][ly - 1][lx]);
                gry = 0.5f * (rawR[sc][ly + 1][lx] - rawR[sc][ly - 1][lx]);
            }

            const int gx = x0 + tx;
            float gix, grx;
            if (gx == 0) {
                gix = rawI[sc][ly][lx + 1] - ic;
                grx = rawR[sc][ly][lx + 1] - rc;
            } else if (gx == DIM - 1) {
                gix = ic - rawI[sc][ly][lx - 1];
                grx = rc - rawR[sc][ly][lx - 1];
            } else {
                gix = 0.5f * (rawI[sc][ly][lx + 1] - rawI[sc][ly][lx - 1]);
                grx = 0.5f * (rawR[sc][ly][lx + 1] - rawR[sc][ly][lx - 1]);
            }

            // fast reciprocals: rel err ~1e-7, absmax budget is 2.3e-3
            const float inv_d = __builtin_amdgcn_rcpf(fmaf(var_i, var_r, 1e-6f));
            const float inv_r = __builtin_amdgcn_rcpf(var_r);
            const float factor = 2.0f * cross * inv_d * (ic - cross * inv_r * rc);

            const size_t CS   = (size_t)DIM * DIM * DIM;
            const size_t base = ((size_t)zc * DIM + gy) * DIM + gx;
            gOut[base]          = -factor * 0.5f * (giz + grz);
            gOut[base + CS]     = -factor * 0.5f * (giy + gry);
            gOut[base + 2 * CS] = -factor * 0.5f * (gix + grx);
        }

        // shift z-history (every iteration)
        #pragma unroll
        for (int f = 0; f < 5; ++f) {
            h[0][f] = h[1][f]; h[1][f] = h[2][f]; h[2][f] = h[3][f]; h[3][f] = n[f];
        }
        __syncthreads();
    }
}

extern "C" void kernel_launch(void* const* d_in, const int* in_sizes, int n_in,
                              void* d_out, int out_size, void* d_ws, size_t ws_size,
                              hipStream_t stream) {
    const float* img = (const float*)d_in[0];  // image
    const float* ref = (const float*)d_in[2];  // reference_image
    float* out = (float*)d_out;

    dim3 grid(DIM / TX, DIM / TY, DIM / ZCH);  // 8 x 32 x 4 = 1024 blocks (full residency)
    ncc_forces_kernel<<<grid, NT, 0, stream>>>(img, ref, out);
}